// Round 12
// baseline (286.489 us; speedup 1.0000x reference)
//
#include <hip/hip_runtime.h>
#include <hip/hip_bf16.h>

#define L_ 4
#define B_ 256
#define C_ 512
#define N_ 50000
#define K_ 20
#define NLIST 21
#define NCH 128       // chunks per l: chunk = 390/391 rows -> 7 tiles of 64
#define BIGF 3.0e38f
#define BN 64         // bank rows per n-tile
#define NW 8          // K-windows per tile, K=64 each
#define NT_ 7         // tiles per chunk

// LDS byte map (per block)
#define BS0_O 0u       // 64 rows x 128B bf16 (K=64 window)
#define BS1_O 8192u
#define B2V_O 16384u   // 64 f32
#define SD_O  16640u   // 256 x 34 f32 = 34816 -> ends 51456
#define SMEM_BYTES 51456
// mg (512 x 22 f32 = 45056B) aliases BS/b2v/sd after chunk-final barrier

typedef __attribute__((ext_vector_type(8))) short short8;
typedef __attribute__((ext_vector_type(4))) float f32x4;

__device__ __forceinline__ unsigned pk2(float lo, float hi) {
    __hip_bfloat162 h = __float22bfloat162_rn(make_float2(lo, hi));
    return *reinterpret_cast<unsigned*>(&h);
}
__device__ __forceinline__ float sq4(float4 v) {
    return v.x*v.x + v.y*v.y + v.z*v.z + v.w*v.w;
}

// LDS-only barrier: outstanding GLOBAL (register) loads stay in flight;
// register hazards are compiler-tracked vmcnt waits (order-safe by construction)
#define LGKM_BAR() do { asm volatile("s_waitcnt lgkmcnt(0)" ::: "memory"); \
                        __builtin_amdgcn_s_barrier(); } while (0)

// ---------------- Phase 1: q (bf16) = mean_s feats, FRAGMENT-MAJOR layout ----
// qbf index = ((((l*16+kb)*8 + band)*2 + m)*4 + r_hi)*128 + c_lo*8 + e
// -> a wave's MFMA A-frag (kb, band=wv, m) is 64 lanes x 16B CONTIGUOUS.
__global__ void qmean_kernel(const float* __restrict__ feats,
                             unsigned short* __restrict__ qbf)
{
    int gtid = blockIdx.x * 256 + threadIdx.x;
    int wid  = gtid >> 6;
    int lane = threadIdx.x & 63;
    const float4* src = reinterpret_cast<const float4*>(feats) + (size_t)wid * 64 + lane;
    float4 v = *src;
    float s = v.x + v.y + v.z + v.w;
    s += __shfl_xor(s, 1); s += __shfl_xor(s, 2);
    s += __shfl_xor(s, 4); s += __shfl_xor(s, 8);
    if ((lane & 15) == 0) {
        const int flat = wid * 4 + (lane >> 4);   // (l*B + b)*C + c
        const int c    = flat & (C_ - 1);
        const int rowg = flat >> 9;
        const int l    = rowg >> 8;
        const int b    = rowg & (B_ - 1);
        const int kb = c >> 5, rh = (c >> 3) & 3, e = c & 7;
        const int band = b >> 5, m = (b >> 4) & 1, cl = b & 15;
        const size_t idx =
            ((size_t)(((l*16 + kb)*8 + band)*2 + m)*4 + rh)*128 + cl*8 + e;
        __hip_bfloat16 h = __float2bfloat16(s * (1.0f / 64.0f));
        qbf[idx] = *reinterpret_cast<unsigned short*>(&h);
    }
}

// ---------------- Phase 2: K=64-window MFMA cross-GEMM + top-21 ----------------
__global__ __launch_bounds__(512, 4)
void dist_topk_kernel(const float* __restrict__ bank,
                      const unsigned short* __restrict__ qbf,
                      float* __restrict__ lists)
{
    __shared__ __align__(16) unsigned char smem[SMEM_BYTES];
    float* b2v = reinterpret_cast<float*>(smem + B2V_O);
    float* sd  = reinterpret_cast<float*>(smem + SD_O);
    float* mg  = reinterpret_cast<float*>(smem);

    const int tid = threadIdx.x;
    const int l   = blockIdx.x >> 7;
    const int nc  = blockIdx.x & 127;

    const float* bb = bank + (size_t)l * N_ * C_;
    const int n0   = (nc * 3125) >> 3;          // nc * 390.625
    const int n1   = ((nc + 1) * 3125) >> 3;
    const int n1m1 = n1 - 1;

    const int lane = tid & 63;
    const int wv   = tid >> 6;                  // wave owns q-rows wv*32..+31
    const int c_lo = lane & 15;
    const int r_hi = lane >> 4;

    // A-frag base (frag-major Q): frag (m,kb) at qf + kb*8192 + m*512
    const unsigned short* qf = qbf + (size_t)l * 131072 + wv * 1024 + lane * 8;

    // B staging: row = tid>>3 (8 thr/row), thread owns one 16B bf16 slot.
    // LDS dst linear (tid*16); SOURCE k pre-swizzled so phys slot p holds
    // logical p^(row&7) (m173 both-sides pattern).
    const int brow   = tid >> 3;
    const int b_srck = (((tid & 7) ^ (brow & 7)) << 3);   // f32 elems in window
    const unsigned b_dst = (unsigned)tid << 4;

    // B fragment read offsets: (n, kb): row=n*16+c_lo, slot=(kb*4+r_hi)^(row&7)
    unsigned offB[4][2];
#pragma unroll
    for (int n = 0; n < 4; ++n) {
        const int row = n*16 + c_lo;
#pragma unroll
        for (int kb = 0; kb < 2; ++kb)
            offB[n][kb] = (unsigned)(row*128 + (((kb*4 + r_hi) ^ (row & 7)) << 4));
    }

    float list[NLIST];
#pragma unroll
    for (int i = 0; i < NLIST; ++i) list[i] = BIGF;

    float4 ring[4][2];       // B ring: slot d&3 holds window-data d (32B f32)
    short8 a1m0, a1m1;       // A frags, even kb (prefetched 1 window ahead)
    short8 a2m0, a2m1;       // A frags, odd kb (intra-window)
    float  b2a = 0.f, b2_keep = 0.f;

    // ---- chunk prologue: ring data0..3; write data0 -> BS0; A window-0 kb0 ----
    {
        const float* ba0 = bb + (size_t)min(n0 + brow, n1m1) * C_ + b_srck;
#pragma unroll
        for (int d = 0; d < 4; ++d) {
            ring[d][0] = *reinterpret_cast<const float4*>(
                reinterpret_cast<const char*>(ba0) + d * 256);
            ring[d][1] = *reinterpret_cast<const float4*>(
                reinterpret_cast<const char*>(ba0) + d * 256 + 16);
        }
        a1m0 = *reinterpret_cast<const short8*>(qf);
        a1m1 = *reinterpret_cast<const short8*>(qf + 512);
        const float4 v0 = ring[0][0], v1 = ring[0][1];
        b2a = sq4(v0) + sq4(v1);
        union { short8 s; unsigned u[4]; } pk;
        pk.u[0] = pk2(v0.x,v0.y); pk.u[1] = pk2(v0.z,v0.w);
        pk.u[2] = pk2(v1.x,v1.y); pk.u[3] = pk2(v1.z,v1.w);
        *reinterpret_cast<short8*>(smem + BS0_O + b_dst) = pk.s;
        LGKM_BAR();
    }

#pragma unroll 1
    for (int t = 0; t < NT_; ++t) {
        const int nt = n0 + t * BN;
        const float* baddrA = bb + (size_t)min(nt + brow,      n1m1) * C_ + b_srck;
        const float* baddrB = bb + (size_t)min(nt + BN + brow, n1m1) * C_ + b_srck;

        f32x4 acc[2][4];
#pragma unroll
        for (int m = 0; m < 2; ++m)
#pragma unroll
            for (int n = 0; n < 4; ++n) acc[m][n] = (f32x4){0.f, 0.f, 0.f, 0.f};

        // ---- 8 windows fully unrolled (K=64 each): static ring/buffer indices ----
#pragma unroll
        for (int w = 0; w < NW; ++w) {
            // WRITEB: window-data(w+1) from ring -> BS[(w+1)&1]
            {
                const float4 v0 = ring[(w + 1) & 3][0], v1 = ring[(w + 1) & 3][1];
                const float s2 = sq4(v0) + sq4(v1);
                if (w == NW - 1) { b2_keep = b2a; b2a = s2; } else b2a += s2;
                union { short8 s; unsigned u[4]; } pk;
                pk.u[0] = pk2(v0.x,v0.y); pk.u[1] = pk2(v0.z,v0.w);
                pk.u[2] = pk2(v1.x,v1.y); pk.u[3] = pk2(v1.z,v1.w);
                *reinterpret_cast<short8*>(smem + ((w + 1) & 1 ? BS1_O : BS0_O) + b_dst) = pk.s;
            }
            // ring load window-data(w+4) -> slot w&3 (3-window HBM cover)
            {
                const float* ba = (w < 4) ? baddrA : baddrB;
                const int d = (w + 4) & 7;
                ring[w & 3][0] = *reinterpret_cast<const float4*>(
                    reinterpret_cast<const char*>(ba) + d * 256);
                ring[w & 3][1] = *reinterpret_cast<const float4*>(
                    reinterpret_cast<const char*>(ba) + d * 256 + 16);
            }
            // A frags, odd kb of this window (L2; covered by kb0 MFMA block)
            a2m0 = *reinterpret_cast<const short8*>(qf + (2*w + 1) * 8192);
            a2m1 = *reinterpret_cast<const short8*>(qf + (2*w + 1) * 8192 + 512);
            // MFMA kb=0 with a1
            {
                const unsigned bso = (w & 1) ? BS1_O : BS0_O;
#pragma unroll
                for (int n = 0; n < 4; ++n) {
                    const short8 bn = *reinterpret_cast<const short8*>(smem + bso + offB[n][0]);
                    acc[0][n] = __builtin_amdgcn_mfma_f32_16x16x32_bf16(a1m0, bn, acc[0][n], 0, 0, 0);
                    acc[1][n] = __builtin_amdgcn_mfma_f32_16x16x32_bf16(a1m1, bn, acc[1][n], 0, 0, 0);
                }
            }
            // A frags, even kb of NEXT window (tile-periodic: (w+1)&7)
            a1m0 = *reinterpret_cast<const short8*>(qf + (2*((w + 1) & 7)) * 8192);
            a1m1 = *reinterpret_cast<const short8*>(qf + (2*((w + 1) & 7)) * 8192 + 512);
            // MFMA kb=1 with a2
            {
                const unsigned bso = (w & 1) ? BS1_O : BS0_O;
#pragma unroll
                for (int n = 0; n < 4; ++n) {
                    const short8 bn = *reinterpret_cast<const short8*>(smem + bso + offB[n][1]);
                    acc[0][n] = __builtin_amdgcn_mfma_f32_16x16x32_bf16(a2m0, bn, acc[0][n], 0, 0, 0);
                    acc[1][n] = __builtin_amdgcn_mfma_f32_16x16x32_bf16(a2m1, bn, acc[1][n], 0, 0, 0);
                }
            }
            LGKM_BAR();
        }

        // ---- b2 reduction: 8 threads/row via shfl over adjacent lanes ----
        {
            float v = b2_keep;
            v += __shfl_xor(v, 1); v += __shfl_xor(v, 2); v += __shfl_xor(v, 4);
            if ((tid & 7) == 0) b2v[brow] = v;
        }
        LGKM_BAR();

        // ---- dump + scan, two 32-col phases; final scan has NO trailing
        //      barrier (overlaps next tile's load-bound first window; sd is
        //      disjoint from BS and rewritten only at the next epilogue) ----
#pragma unroll
        for (int ph = 0; ph < 2; ++ph) {
            // C/D layout: col = lane&15, row = (lane>>4)*4 + reg
#pragma unroll
            for (int m = 0; m < 2; ++m)
#pragma unroll
                for (int nn = 0; nn < 2; ++nn) {
                    const int n    = 2*ph + nn;
                    const int col  = 16*n + c_lo;
                    const int lcol = 16*nn + c_lo;
                    const float bv = b2v[col];
                    const bool ok  = (nt + col) < n1;
#pragma unroll
                    for (int rg = 0; rg < 4; ++rg) {
                        const int row = wv*32 + m*16 + r_hi*4 + rg;
                        const float v = fmaf(-2.0f, acc[m][n][rg], bv);
                        sd[row*34 + lcol] = ok ? v : BIGF;
                    }
                }
            LGKM_BAR();
            // scan: 2 threads per row, 16 cols each, batch-4 prefilter
            {
                const float* srow = sd + (tid >> 1)*34 + ((tid & 1) << 4);
#pragma unroll
                for (int bt = 0; bt < 4; ++bt) {
                    const float2 u = *reinterpret_cast<const float2*>(srow + (bt << 2));
                    const float2 w2 = *reinterpret_cast<const float2*>(srow + (bt << 2) + 2);
                    const float m4 = fminf(fminf(u.x, u.y), fminf(w2.x, w2.y));
                    if (m4 < list[NLIST-1]) {
                        float cand[4] = {u.x, u.y, w2.x, w2.y};
#pragma unroll
                        for (int c4 = 0; c4 < 4; ++c4) {
                            float v = cand[c4];
                            if (v < list[NLIST-1]) {
#pragma unroll
                                for (int i = 0; i < NLIST; ++i) {
                                    const float lo = fminf(list[i], v);
                                    const float hi = fmaxf(list[i], v);
                                    list[i] = lo; v = hi;
                                }
                            }
                        }
                    }
                }
            }
            if (ph == 0) LGKM_BAR();   // before ph1 dump overwrites sd
        }
    }

    // ---- chunk end: sync scans, then merge 2 per-row sublists ----
    LGKM_BAR();
#pragma unroll
    for (int i = 0; i < NLIST; ++i) mg[tid*22 + i] = list[i];
    LGKM_BAR();
    if ((tid & 1) == 0) {
        const int row = tid >> 1;
        float* outp = lists + ((size_t)(l*B_ + row)*NCH + nc)*NLIST;
        const float* g0 = mg + tid*22;
        const float* g1 = mg + (tid + 1)*22;
        int p0 = 0, p1 = 0;
#pragma unroll 1
        for (int i = 0; i < NLIST; ++i) {
            const float h0 = (p0 < NLIST) ? g0[p0] : BIGF;
            const float h1 = (p1 < NLIST) ? g1[p1] : BIGF;
            if (h0 <= h1) { outp[i] = h0; ++p0; }
            else          { outp[i] = h1; ++p1; }
        }
    }
}

// ---------------- Phase 3: merge 128 sorted chunk-lists per (l,b), LID ----------------
__global__ void lid_kernel(const float* __restrict__ lists,
                           const unsigned short* __restrict__ qbf,
                           float* __restrict__ out)
{
    __shared__ float pops[4][NLIST];
    const int lane = threadIdx.x & 63;
    const int w    = threadIdx.x >> 6;
    const int gw   = blockIdx.x * 4 + w;   // 0..1023 = (l,b)
    const int l    = gw & 3;
    const int b    = gw >> 2;

    // q2 from fragment-major layout: lane covers (kb=lane>>2, r_hi=lane&3)
    const size_t qidx =
        ((size_t)(((l*16 + (lane >> 2))*8 + (b >> 5))*2 + ((b >> 4) & 1))*4 + (lane & 3))*128
        + (size_t)(b & 15)*8;
    short8 qv = *reinterpret_cast<const short8*>(qbf + qidx);
    float q2 = 0.f;
#pragma unroll
    for (int i = 0; i < 8; ++i) {
        unsigned u = ((unsigned)(unsigned short)qv[i]) << 16;
        float f = __uint_as_float(u);
        q2 += f*f;
    }
    q2 += __shfl_xor(q2,1); q2 += __shfl_xor(q2,2); q2 += __shfl_xor(q2,4);
    q2 += __shfl_xor(q2,8); q2 += __shfl_xor(q2,16); q2 += __shfl_xor(q2,32);

    // 128 lists: lane owns chunks {lane, lane+64}
    const float* base = lists + (size_t)(l*B_ + b) * NCH * NLIST;
    int p0 = 0, p1 = 0;
#pragma unroll 1
    for (int i = 0; i < NLIST; ++i) {
        const float h0 = (p0 < NLIST) ? base[(size_t)lane*NLIST + p0] : BIGF;
        const float h1 = (p1 < NLIST) ? base[(size_t)(lane+64)*NLIST + p1] : BIGF;
        const float h  = fminf(h0, h1);
        float m = h;
        m = fminf(m, __shfl_xor(m,1));  m = fminf(m, __shfl_xor(m,2));
        m = fminf(m, __shfl_xor(m,4));  m = fminf(m, __shfl_xor(m,8));
        m = fminf(m, __shfl_xor(m,16)); m = fminf(m, __shfl_xor(m,32));
        const unsigned long long ball = __ballot(h == m);
        if (lane == __ffsll(ball) - 1) {
            if (h0 == m) ++p0;
            else         ++p1;
        }
        if (lane == 0) pops[w][i] = fmaxf(q2 + m, 0.f);
    }
    __syncthreads();

    const float r2 = pops[w][NLIST-1];
    float t = 0.f;
    if (lane >= 1 && lane < NLIST) t = 0.5f * logf(pops[w][lane] / r2);
    t += __shfl_xor(t,1); t += __shfl_xor(t,2); t += __shfl_xor(t,4);
    t += __shfl_xor(t,8); t += __shfl_xor(t,16); t += __shfl_xor(t,32);

    if (lane == 0) out[(size_t)b * L_ + l] = -(float)K_ / t;
}

extern "C" void kernel_launch(void* const* d_in, const int* in_sizes, int n_in,
                              void* d_out, int out_size, void* d_ws, size_t ws_size,
                              hipStream_t stream)
{
    (void)in_sizes; (void)n_in; (void)out_size; (void)ws_size;
    const float* feats = (const float*)d_in[0];
    const float* bank  = (const float*)d_in[1];
    unsigned short* qbf = (unsigned short*)d_ws;                 // 1 MiB bf16 q (frag-major)
    float* lists = (float*)((char*)d_ws + (size_t)L_*B_*C_*2);   // 11 MiB chunk lists

    qmean_kernel<<<32768, 256, 0, stream>>>(feats, qbf);
    dist_topk_kernel<<<L_*NCH, 512, 0, stream>>>(bank, qbf, lists);
    lid_kernel<<<256, 256, 0, stream>>>(lists, qbf, (float*)d_out);
}